// Round 2
// baseline (2076.172 us; speedup 1.0000x reference)
//
#include <hip/hip_runtime.h>
#include <hip/hip_bf16.h>

#define VOCAB  96
#define EMBED  32
#define HIDDEN 128
#define BATCH  512
#define TLEN   2048
#define KW     (EMBED + HIDDEN)   // 160
#define MROWS  (BATCH * TLEN)     // 1,048,576

typedef __attribute__((ext_vector_type(8))) short short8;    // 8 x bf16 bits
typedef __attribute__((ext_vector_type(4))) float float4v;

static __device__ __forceinline__ unsigned short f2bf_bits(float f) {
    __hip_bfloat16 b = __float2bfloat16(f);
    return *(unsigned short*)&b;
}

// ---------------------------------------------------------------------------
// Kernel A: Pe[v][i] = b_cell[i] + sum_k emb[v,k] * We[i,k]   (96 x 128, fp32)
// Exact fp32 — feeds the MFMA C operand, so emb/We/bias carry NO bf16 error.
// ---------------------------------------------------------------------------
__global__ void pe_precompute(const float* __restrict__ emb,
                              const float* __restrict__ W_cell,
                              const float* __restrict__ b_cell,
                              float* __restrict__ Pe) {
    const int tid = blockIdx.x * blockDim.x + threadIdx.x;
    if (tid >= VOCAB * HIDDEN) return;
    const int v = tid >> 7;
    const int i = tid & (HIDDEN - 1);
    float acc = b_cell[i];
    const float* e = emb + v * EMBED;
    const float* w = W_cell + i * KW;
    #pragma unroll
    for (int k = 0; k < EMBED; ++k) acc = fmaf(e[k], w[k], acc);
    Pe[tid] = acc;
}

// ---------------------------------------------------------------------------
// Fused recurrence + decode. One block = 16 batch rows, 4 waves (256 thr).
// MFMA operand-swapped: A = weights (m = hidden/vocab), B = h (n = batch16).
//   A-frag: A[m=lane&15][k=quad*8+j]  (W rows live in registers all kernel)
//   B-frag: B[k=quad*8+j][n=lane&15]  (h of batch row lane&15)
//   D:      D[m=quad*4+r][n=lane&15]
// h carried as hi+lo bf16 split (≈16-bit mantissa) to keep recurrence error
// at the shipped kernel's level. Pe[tok] fp32 is the MFMA C-init (exact).
// Wave w: rec m-tiles {2w,2w+1}; dec v-tiles w<2 ? {2w,2w+1} : {w+2}.
// Single s_barrier per step (double-buffered h exchange); out stores are
// fire-and-forget (no vmcnt drain in the loop).
// ---------------------------------------------------------------------------
__global__ __launch_bounds__(256, 1)
void rnn_fused(const int* __restrict__ x,
               const float* __restrict__ h0,
               const float* __restrict__ W_cell,
               const float* __restrict__ W_dec,
               const float* __restrict__ b_dec,
               const float* __restrict__ Pe,
               float* __restrict__ out) {
    __shared__ float pe_lds[VOCAB][132];                    // 50.7 KB (pad->2-way)
    __shared__ unsigned char xT[TLEN][16];                  // 32 KB, transposed tokens
    __shared__ __align__(16) unsigned short hb_hi[2][16][136];  // 8.5 KB (272B stride)
    __shared__ __align__(16) unsigned short hb_lo[2][16][136];  // 8.5 KB

    const int tid  = threadIdx.x;
    const int wave = tid >> 6;
    const int lane = tid & 63;
    const int l16  = lane & 15;
    const int q    = lane >> 4;
    const int mt0  = wave * 2;                  // rec m-tiles {mt0, mt0+1}
    const int vt0  = (wave < 2) ? wave * 2 : wave + 2;
    const int nvt  = (wave < 2) ? 2 : 1;
    const int rowbase = blockIdx.x * 16;
    const int brow = rowbase + l16;             // this lane's batch row (n-column)

    // ---- prologue: LDS fills ----
    for (int n = tid; n < VOCAB * HIDDEN; n += 256)
        pe_lds[n >> 7][n & 127] = Pe[n];
    for (int n = tid; n < 16 * TLEN; n += 256) {
        const int r = n >> 11, c = n & (TLEN - 1);
        xT[c][r] = (unsigned char)x[(size_t)(rowbase + r) * TLEN + c];
    }

    // ---- per-wave constant A-fragments (bf16, registers) ----
    short8 Wh[2][4], Wd[2][4];
    #pragma unroll
    for (int m = 0; m < 2; ++m) {
        const float* rp = W_cell + (size_t)((mt0 + m) * 16 + l16) * KW + EMBED + q * 8;
        #pragma unroll
        for (int kt = 0; kt < 4; ++kt) {
            const float4 f0 = *(const float4*)(rp + kt * 32);
            const float4 f1 = *(const float4*)(rp + kt * 32 + 4);
            short8 s;
            s[0]=(short)f2bf_bits(f0.x); s[1]=(short)f2bf_bits(f0.y);
            s[2]=(short)f2bf_bits(f0.z); s[3]=(short)f2bf_bits(f0.w);
            s[4]=(short)f2bf_bits(f1.x); s[5]=(short)f2bf_bits(f1.y);
            s[6]=(short)f2bf_bits(f1.z); s[7]=(short)f2bf_bits(f1.w);
            Wh[m][kt] = s;
        }
    }
    float4 bdec[2];
    #pragma unroll
    for (int v = 0; v < 2; ++v) {
        if (v < nvt) {
            const float* rp = W_dec + (size_t)((vt0 + v) * 16 + l16) * HIDDEN + q * 8;
            #pragma unroll
            for (int kt = 0; kt < 4; ++kt) {
                const float4 f0 = *(const float4*)(rp + kt * 32);
                const float4 f1 = *(const float4*)(rp + kt * 32 + 4);
                short8 s;
                s[0]=(short)f2bf_bits(f0.x); s[1]=(short)f2bf_bits(f0.y);
                s[2]=(short)f2bf_bits(f0.z); s[3]=(short)f2bf_bits(f0.w);
                s[4]=(short)f2bf_bits(f1.x); s[5]=(short)f2bf_bits(f1.y);
                s[6]=(short)f2bf_bits(f1.z); s[7]=(short)f2bf_bits(f1.w);
                Wd[v][kt] = s;
            }
            bdec[v] = *(const float4*)(b_dec + (vt0 + v) * 16 + q * 4);
        }
    }

    // ---- initial B-frags from h0 (fp32 -> exact hi+lo split) ----
    short8 Bhi[4], Blo[4];
    #pragma unroll
    for (int kt = 0; kt < 4; ++kt) {
        const float* hp = h0 + (size_t)brow * HIDDEN + kt * 32 + q * 8;
        const float4 f0 = *(const float4*)hp;
        const float4 f1 = *(const float4*)(hp + 4);
        const float hv8[8] = {f0.x, f0.y, f0.z, f0.w, f1.x, f1.y, f1.z, f1.w};
        short8 hi, lo;
        #pragma unroll
        for (int j = 0; j < 8; ++j) {
            const unsigned hb = __float_as_uint(hv8[j]) & 0xffff0000u;
            hi[j] = (short)(hb >> 16);
            lo[j] = (short)f2bf_bits(hv8[j] - __uint_as_float(hb));
        }
        Bhi[kt] = hi; Blo[kt] = lo;
    }

    __syncthreads();   // xT / pe_lds ready (one full sync, outside the hot loop)

    int tokC = xT[0][l16];          // token for step t   (t=0)
    int tokN = xT[1][l16];          // token for step t+1
    float4 pc0 = *(const float4*)&pe_lds[tokC][ mt0      * 16 + q * 4];
    float4 pc1 = *(const float4*)&pe_lds[tokC][(mt0 + 1) * 16 + q * 4];

    float hv[2][4];                 // last fp32 h values (h_final)

    for (int t = 0; t < TLEN; ++t) {
        // --- prefetch Pe for step t+1 and token t+2 (read-only LDS, no barrier dep)
        const float4 pn0 = *(const float4*)&pe_lds[tokN][ mt0      * 16 + q * 4];
        const float4 pn1 = *(const float4*)&pe_lds[tokN][(mt0 + 1) * 16 + q * 4];
        const int t2 = (t + 2 < TLEN) ? t + 2 : TLEN - 1;
        const int tokN2 = xT[t2][l16];

        // --- decode: out_{t-1} = W_dec · h_t + b_dec (B-frags = current h)
        float4v d0 = {bdec[0].x, bdec[0].y, bdec[0].z, bdec[0].w};
        float4v d1 = {bdec[1].x, bdec[1].y, bdec[1].z, bdec[1].w};
        #pragma unroll
        for (int kt = 0; kt < 4; ++kt) {
            d0 = __builtin_amdgcn_mfma_f32_16x16x32_bf16(Wd[0][kt], Bhi[kt], d0, 0, 0, 0);
            if (nvt > 1)
                d1 = __builtin_amdgcn_mfma_f32_16x16x32_bf16(Wd[1][kt], Bhi[kt], d1, 0, 0, 0);
        }
        #pragma unroll
        for (int kt = 0; kt < 4; ++kt) {
            d0 = __builtin_amdgcn_mfma_f32_16x16x32_bf16(Wd[0][kt], Blo[kt], d0, 0, 0, 0);
            if (nvt > 1)
                d1 = __builtin_amdgcn_mfma_f32_16x16x32_bf16(Wd[1][kt], Blo[kt], d1, 0, 0, 0);
        }
        if (t) {   // fire-and-forget float4 stores (never drained in-loop)
            float* op = out + ((size_t)brow * TLEN + (t - 1)) * VOCAB;
            *(float4v*)(op + vt0 * 16 + q * 4) = d0;
            if (nvt > 1) *(float4v*)(op + (vt0 + 1) * 16 + q * 4) = d1;
        }

        // --- recurrence: acc = Pe[tok_t] + Wh·(h_hi + h_lo), 4 parallel chains
        float4v ah0 = {pc0.x, pc0.y, pc0.z, pc0.w};
        float4v ah1 = {pc1.x, pc1.y, pc1.z, pc1.w};
        float4v al0 = {0.f, 0.f, 0.f, 0.f};
        float4v al1 = {0.f, 0.f, 0.f, 0.f};
        #pragma unroll
        for (int kt = 0; kt < 4; ++kt) {
            ah0 = __builtin_amdgcn_mfma_f32_16x16x32_bf16(Wh[0][kt], Bhi[kt], ah0, 0, 0, 0);
            ah1 = __builtin_amdgcn_mfma_f32_16x16x32_bf16(Wh[1][kt], Bhi[kt], ah1, 0, 0, 0);
            al0 = __builtin_amdgcn_mfma_f32_16x16x32_bf16(Wh[0][kt], Blo[kt], al0, 0, 0, 0);
            al1 = __builtin_amdgcn_mfma_f32_16x16x32_bf16(Wh[1][kt], Blo[kt], al1, 0, 0, 0);
        }
        #pragma unroll
        for (int r = 0; r < 4; ++r) {
            const float s0 = ah0[r] + al0[r];
            const float s1 = ah1[r] + al1[r];
            // tanh(x) = 1 - 2/(exp(2x)+1); inf-safe, no clamp needed
            const float e0 = __expf(2.f * s0);
            const float e1 = __expf(2.f * s1);
            hv[0][r] = 1.f - __fdividef(2.f, e0 + 1.f);
            hv[1][r] = 1.f - __fdividef(2.f, e1 + 1.f);
        }

        // --- exact hi/lo split, pack pairs, write h_{t+1} to the other buffer
        const int pn = (t & 1) ^ 1;
        #pragma unroll
        for (int m = 0; m < 2; ++m) {
            const unsigned b0 = __float_as_uint(hv[m][0]) & 0xffff0000u;
            const unsigned b1 = __float_as_uint(hv[m][1]) & 0xffff0000u;
            const unsigned b2 = __float_as_uint(hv[m][2]) & 0xffff0000u;
            const unsigned b3 = __float_as_uint(hv[m][3]) & 0xffff0000u;
            const float l0 = hv[m][0] - __uint_as_float(b0);
            const float l1 = hv[m][1] - __uint_as_float(b1);
            const float l2 = hv[m][2] - __uint_as_float(b2);
            const float l3 = hv[m][3] - __uint_as_float(b3);
            uint2 hw, lw;
            hw.x = (b0 >> 16) | b1;
            hw.y = (b2 >> 16) | b3;
            lw.x = (unsigned)f2bf_bits(l0) | ((unsigned)f2bf_bits(l1) << 16);
            lw.y = (unsigned)f2bf_bits(l2) | ((unsigned)f2bf_bits(l3) << 16);
            const int mcol = (mt0 + m) * 16 + q * 4;
            *(uint2*)&hb_hi[pn][l16][mcol] = hw;
            *(uint2*)&hb_lo[pn][l16][mcol] = lw;
        }

        // LDS writes visible, barrier — WITHOUT vmcnt(0) store drain
        asm volatile("s_waitcnt lgkmcnt(0)" ::: "memory");
        __builtin_amdgcn_s_barrier();
        asm volatile("" ::: "memory");

        // --- next-step B-frags (each lane reads its own batch row's full h)
        #pragma unroll
        for (int kt = 0; kt < 4; ++kt) {
            Bhi[kt] = *(const short8*)&hb_hi[pn][l16][kt * 32 + q * 8];
            Blo[kt] = *(const short8*)&hb_lo[pn][l16][kt * 32 + q * 8];
        }
        pc0 = pn0; pc1 = pn1;
        tokC = tokN; tokN = tokN2;
    }

    // ---- epilogue: decode out_{TLEN-1} from h_TLEN ----
    {
        float4v d0 = {bdec[0].x, bdec[0].y, bdec[0].z, bdec[0].w};
        float4v d1 = {bdec[1].x, bdec[1].y, bdec[1].z, bdec[1].w};
        #pragma unroll
        for (int kt = 0; kt < 4; ++kt) {
            d0 = __builtin_amdgcn_mfma_f32_16x16x32_bf16(Wd[0][kt], Bhi[kt], d0, 0, 0, 0);
            if (nvt > 1)
                d1 = __builtin_amdgcn_mfma_f32_16x16x32_bf16(Wd[1][kt], Bhi[kt], d1, 0, 0, 0);
        }
        #pragma unroll
        for (int kt = 0; kt < 4; ++kt) {
            d0 = __builtin_amdgcn_mfma_f32_16x16x32_bf16(Wd[0][kt], Blo[kt], d0, 0, 0, 0);
            if (nvt > 1)
                d1 = __builtin_amdgcn_mfma_f32_16x16x32_bf16(Wd[1][kt], Blo[kt], d1, 0, 0, 0);
        }
        float* op = out + ((size_t)brow * TLEN + (TLEN - 1)) * VOCAB;
        *(float4v*)(op + vt0 * 16 + q * 4) = d0;
        if (nvt > 1) *(float4v*)(op + (vt0 + 1) * 16 + q * 4) = d1;
    }

    // ---- h_final (fp32) ----
    #pragma unroll
    for (int m = 0; m < 2; ++m) {
        #pragma unroll
        for (int r = 0; r < 4; ++r) {
            out[(size_t)MROWS * VOCAB + (size_t)brow * HIDDEN
                + (mt0 + m) * 16 + q * 4 + r] = hv[m][r];
        }
    }
}

extern "C" void kernel_launch(void* const* d_in, const int* in_sizes, int n_in,
                              void* d_out, int out_size, void* d_ws, size_t ws_size,
                              hipStream_t stream) {
    const int*   x      = (const int*)  d_in[0];
    const float* h0     = (const float*)d_in[1];
    const float* emb    = (const float*)d_in[2];
    const float* W_cell = (const float*)d_in[3];
    const float* b_cell = (const float*)d_in[4];
    const float* W_dec  = (const float*)d_in[5];
    const float* b_dec  = (const float*)d_in[6];
    float* out = (float*)d_out;

    float* Pe = (float*)d_ws;   // 48 KB

    pe_precompute<<<(VOCAB * HIDDEN + 127) / 128, 128, 0, stream>>>(emb, W_cell, b_cell, Pe);
    rnn_fused<<<BATCH / 16, 256, 0, stream>>>(x, h0, W_cell, W_dec, b_dec, Pe, out);
}

// Round 3
// 1937.214 us; speedup vs baseline: 1.0717x; 1.0717x over previous
//
#include <hip/hip_runtime.h>
#include <hip/hip_bf16.h>

#define VOCAB  96
#define EMBED  32
#define HIDDEN 128
#define BATCH  512
#define TLEN   2048
#define KW     (EMBED + HIDDEN)   // 160
#define MROWS  (BATCH * TLEN)     // 1,048,576

typedef __attribute__((ext_vector_type(8))) short short8;    // 8 x bf16 bits
typedef __attribute__((ext_vector_type(4))) float float4v;

static __device__ __forceinline__ unsigned short f2bf_bits(float f) {
    __hip_bfloat16 b = __float2bfloat16(f);
    return *(unsigned short*)&b;
}

// ---------------------------------------------------------------------------
// Kernel A: Pe[v][i] = b_cell[i] + sum_k emb[v,k] * We[i,k]   (96 x 128, fp32)
// ---------------------------------------------------------------------------
__global__ void pe_precompute(const float* __restrict__ emb,
                              const float* __restrict__ W_cell,
                              const float* __restrict__ b_cell,
                              float* __restrict__ Pe) {
    const int tid = blockIdx.x * blockDim.x + threadIdx.x;
    if (tid >= VOCAB * HIDDEN) return;
    const int v = tid >> 7;
    const int i = tid & (HIDDEN - 1);
    float acc = b_cell[i];
    const float* e = emb + v * EMBED;
    const float* w = W_cell + i * KW;
    #pragma unroll
    for (int k = 0; k < EMBED; ++k) acc = fmaf(e[k], w[k], acc);
    Pe[tid] = acc;
}

// ---------------------------------------------------------------------------
// Fused recurrence + decode. One block = 16 batch rows, 4 waves (256 thr).
// MFMA operand-swapped: A = weights (m = hidden/vocab), B = h (n = batch16).
// h exchange buffer layout [buf][k>>3][n][k&7] makes BOTH the b128 reads
// (addr = lane*16, perfectly linear) and the b64 writes (2 lanes/bank)
// bank-conflict-free. Body order: B-read -> rec MFMA -> decode MFMA ->
// tanh/split (VALU overlaps decode on the MFMA pipe) -> LDS write -> store
// -> lgkmcnt(0) -> s_barrier.  No vmcnt drain in the loop.
// ---------------------------------------------------------------------------
__global__ __launch_bounds__(256, 1)
void rnn_fused(const int* __restrict__ x,
               const float* __restrict__ h0,
               const float* __restrict__ W_cell,
               const float* __restrict__ W_dec,
               const float* __restrict__ b_dec,
               const float* __restrict__ Pe,
               float* __restrict__ out) {
    __shared__ float pe_lds[VOCAB][HIDDEN];                 // 48 KB (reads broadcast)
    __shared__ unsigned char xT[TLEN][16];                  // 32 KB transposed tokens
    __shared__ __align__(16) unsigned short hb_hi[2][16][16][8];  // 8 KB
    __shared__ __align__(16) unsigned short hb_lo[2][16][16][8];  // 8 KB

    const int tid  = threadIdx.x;
    const int wave = tid >> 6;
    const int lane = tid & 63;
    const int l16  = lane & 15;
    const int q    = lane >> 4;
    const int mt0  = wave * 2;                  // rec m-tiles {mt0, mt0+1}
    const int vt0  = (wave < 2) ? wave * 2 : wave + 2;
    const int nvt  = (wave < 2) ? 2 : 1;
    const int rowbase = blockIdx.x * 16;
    const int brow = rowbase + l16;             // this lane's batch row (n-column)

    // ---- prologue: LDS fills ----
    for (int n = tid; n < VOCAB * HIDDEN; n += 256)
        pe_lds[n >> 7][n & 127] = Pe[n];
    for (int n = tid; n < 16 * TLEN; n += 256) {
        const int r = n >> 11, c = n & (TLEN - 1);
        xT[c][r] = (unsigned char)x[(size_t)(rowbase + r) * TLEN + c];
    }

    // ---- per-wave constant A-fragments (bf16, registers) ----
    short8 Wh[2][4], Wd[2][4];
    #pragma unroll
    for (int m = 0; m < 2; ++m) {
        const float* rp = W_cell + (size_t)((mt0 + m) * 16 + l16) * KW + EMBED + q * 8;
        #pragma unroll
        for (int kt = 0; kt < 4; ++kt) {
            const float4 f0 = *(const float4*)(rp + kt * 32);
            const float4 f1 = *(const float4*)(rp + kt * 32 + 4);
            short8 s;
            s[0]=(short)f2bf_bits(f0.x); s[1]=(short)f2bf_bits(f0.y);
            s[2]=(short)f2bf_bits(f0.z); s[3]=(short)f2bf_bits(f0.w);
            s[4]=(short)f2bf_bits(f1.x); s[5]=(short)f2bf_bits(f1.y);
            s[6]=(short)f2bf_bits(f1.z); s[7]=(short)f2bf_bits(f1.w);
            Wh[m][kt] = s;
        }
    }
    float4 bdec[2];
    #pragma unroll
    for (int v = 0; v < 2; ++v) {
        if (v < nvt) {
            const float* rp = W_dec + (size_t)((vt0 + v) * 16 + l16) * HIDDEN + q * 8;
            #pragma unroll
            for (int kt = 0; kt < 4; ++kt) {
                const float4 f0 = *(const float4*)(rp + kt * 32);
                const float4 f1 = *(const float4*)(rp + kt * 32 + 4);
                short8 s;
                s[0]=(short)f2bf_bits(f0.x); s[1]=(short)f2bf_bits(f0.y);
                s[2]=(short)f2bf_bits(f0.z); s[3]=(short)f2bf_bits(f0.w);
                s[4]=(short)f2bf_bits(f1.x); s[5]=(short)f2bf_bits(f1.y);
                s[6]=(short)f2bf_bits(f1.z); s[7]=(short)f2bf_bits(f1.w);
                Wd[v][kt] = s;
            }
            bdec[v] = *(const float4*)(b_dec + (vt0 + v) * 16 + q * 4);
        }
    }

    // ---- initial B-frags from h0 (fp32 -> exact hi+lo split) ----
    short8 Bhi[4], Blo[4];
    #pragma unroll
    for (int kt = 0; kt < 4; ++kt) {
        const float* hp = h0 + (size_t)brow * HIDDEN + kt * 32 + q * 8;
        const float4 f0 = *(const float4*)hp;
        const float4 f1 = *(const float4*)(hp + 4);
        const float hv8[8] = {f0.x, f0.y, f0.z, f0.w, f1.x, f1.y, f1.z, f1.w};
        short8 hi, lo;
        #pragma unroll
        for (int j = 0; j < 8; ++j) {
            const unsigned hb = __float_as_uint(hv8[j]) & 0xffff0000u;
            hi[j] = (short)(hb >> 16);
            lo[j] = (short)f2bf_bits(hv8[j] - __uint_as_float(hb));
        }
        Bhi[kt] = hi; Blo[kt] = lo;
    }

    __syncthreads();   // xT / pe_lds ready (one full sync, outside the hot loop)

    int tokC = xT[0][l16];
    int tokN = xT[1][l16];
    float4 pc0 = *(const float4*)&pe_lds[tokC][ mt0      * 16 + q * 4];
    float4 pc1 = *(const float4*)&pe_lds[tokC][(mt0 + 1) * 16 + q * 4];

    float hv[2][4];                 // last fp32 h values (h_final)

    for (int t = 0; t < TLEN; ++t) {
        // --- prefetch Pe for step t+1 and token t+2 (read-only LDS)
        const float4 pn0 = *(const float4*)&pe_lds[tokN][ mt0      * 16 + q * 4];
        const float4 pn1 = *(const float4*)&pe_lds[tokN][(mt0 + 1) * 16 + q * 4];
        const int t2 = (t + 2 < TLEN) ? t + 2 : TLEN - 1;
        const int tokN2 = xT[t2][l16];

        // --- recurrence FIRST: acc = Pe[tok_t] + Wh·(h_hi + h_lo)
        float4v ah0 = {pc0.x, pc0.y, pc0.z, pc0.w};
        float4v ah1 = {pc1.x, pc1.y, pc1.z, pc1.w};
        float4v al0 = {0.f, 0.f, 0.f, 0.f};
        float4v al1 = {0.f, 0.f, 0.f, 0.f};
        #pragma unroll
        for (int kt = 0; kt < 4; ++kt) {
            ah0 = __builtin_amdgcn_mfma_f32_16x16x32_bf16(Wh[0][kt], Bhi[kt], ah0, 0, 0, 0);
            ah1 = __builtin_amdgcn_mfma_f32_16x16x32_bf16(Wh[1][kt], Bhi[kt], ah1, 0, 0, 0);
            al0 = __builtin_amdgcn_mfma_f32_16x16x32_bf16(Wh[0][kt], Blo[kt], al0, 0, 0, 0);
            al1 = __builtin_amdgcn_mfma_f32_16x16x32_bf16(Wh[1][kt], Blo[kt], al1, 0, 0, 0);
        }

        // --- decode (independent; MFMA-pipe issue hides under tanh/split VALU)
        float4v d0 = {bdec[0].x, bdec[0].y, bdec[0].z, bdec[0].w};
        float4v d1 = {bdec[1].x, bdec[1].y, bdec[1].z, bdec[1].w};
        #pragma unroll
        for (int kt = 0; kt < 4; ++kt) {
            d0 = __builtin_amdgcn_mfma_f32_16x16x32_bf16(Wd[0][kt], Bhi[kt], d0, 0, 0, 0);
            if (nvt > 1)
                d1 = __builtin_amdgcn_mfma_f32_16x16x32_bf16(Wd[1][kt], Bhi[kt], d1, 0, 0, 0);
        }
        #pragma unroll
        for (int kt = 0; kt < 4; ++kt) {
            d0 = __builtin_amdgcn_mfma_f32_16x16x32_bf16(Wd[0][kt], Blo[kt], d0, 0, 0, 0);
            if (nvt > 1)
                d1 = __builtin_amdgcn_mfma_f32_16x16x32_bf16(Wd[1][kt], Blo[kt], d1, 0, 0, 0);
        }

        // --- tanh on the 8 rec outputs
        #pragma unroll
        for (int r = 0; r < 4; ++r) {
            const float s0 = ah0[r] + al0[r];
            const float s1 = ah1[r] + al1[r];
            const float e0 = __expf(2.f * s0);
            const float e1 = __expf(2.f * s1);
            hv[0][r] = 1.f - __fdividef(2.f, e0 + 1.f);
            hv[1][r] = 1.f - __fdividef(2.f, e1 + 1.f);
        }

        // --- exact hi/lo split, pack, write h_{t+1} (conflict-free layout)
        const int pn = (t & 1) ^ 1;
        #pragma unroll
        for (int m = 0; m < 2; ++m) {
            const unsigned b0 = __float_as_uint(hv[m][0]) & 0xffff0000u;
            const unsigned b1 = __float_as_uint(hv[m][1]) & 0xffff0000u;
            const unsigned b2 = __float_as_uint(hv[m][2]) & 0xffff0000u;
            const unsigned b3 = __float_as_uint(hv[m][3]) & 0xffff0000u;
            const float l0 = hv[m][0] - __uint_as_float(b0);
            const float l1 = hv[m][1] - __uint_as_float(b1);
            const float l2 = hv[m][2] - __uint_as_float(b2);
            const float l3 = hv[m][3] - __uint_as_float(b3);
            uint2 hw, lw;
            hw.x = (b0 >> 16) | b1;
            hw.y = (b2 >> 16) | b3;
            lw.x = (unsigned)f2bf_bits(l0) | ((unsigned)f2bf_bits(l1) << 16);
            lw.y = (unsigned)f2bf_bits(l2) | ((unsigned)f2bf_bits(l3) << 16);
            // k0 = (mt0+m)*16 + q*4  ->  [k0>>3][n][k0&7]
            const int kq = (mt0 + m) * 2 + (q >> 1);
            const int j0 = (q & 1) * 4;
            *(uint2*)&hb_hi[pn][kq][l16][j0] = hw;
            *(uint2*)&hb_lo[pn][kq][l16][j0] = lw;
        }

        // --- fire-and-forget decode stores (results settled long ago)
        if (t) {
            float* op = out + ((size_t)brow * TLEN + (t - 1)) * VOCAB;
            *(float4v*)(op + vt0 * 16 + q * 4) = d0;
            if (nvt > 1) *(float4v*)(op + (vt0 + 1) * 16 + q * 4) = d1;
        }

        // LDS writes visible, barrier — WITHOUT vmcnt(0) store drain
        asm volatile("s_waitcnt lgkmcnt(0)" ::: "memory");
        __builtin_amdgcn_s_barrier();
        asm volatile("" ::: "memory");

        // --- next-step B-frags: addr = lane*16 (linear, conflict-free)
        #pragma unroll
        for (int kt = 0; kt < 4; ++kt) {
            Bhi[kt] = *(const short8*)&hb_hi[pn][kt * 4 + q][l16][0];
            Blo[kt] = *(const short8*)&hb_lo[pn][kt * 4 + q][l16][0];
        }
        pc0 = pn0; pc1 = pn1;
        tokC = tokN; tokN = tokN2;
    }

    // ---- epilogue: decode out_{TLEN-1} from h_TLEN ----
    {
        float4v d0 = {bdec[0].x, bdec[0].y, bdec[0].z, bdec[0].w};
        float4v d1 = {bdec[1].x, bdec[1].y, bdec[1].z, bdec[1].w};
        #pragma unroll
        for (int kt = 0; kt < 4; ++kt) {
            d0 = __builtin_amdgcn_mfma_f32_16x16x32_bf16(Wd[0][kt], Bhi[kt], d0, 0, 0, 0);
            if (nvt > 1)
                d1 = __builtin_amdgcn_mfma_f32_16x16x32_bf16(Wd[1][kt], Bhi[kt], d1, 0, 0, 0);
        }
        #pragma unroll
        for (int kt = 0; kt < 4; ++kt) {
            d0 = __builtin_amdgcn_mfma_f32_16x16x32_bf16(Wd[0][kt], Blo[kt], d0, 0, 0, 0);
            if (nvt > 1)
                d1 = __builtin_amdgcn_mfma_f32_16x16x32_bf16(Wd[1][kt], Blo[kt], d1, 0, 0, 0);
        }
        float* op = out + ((size_t)brow * TLEN + (TLEN - 1)) * VOCAB;
        *(float4v*)(op + vt0 * 16 + q * 4) = d0;
        if (nvt > 1) *(float4v*)(op + (vt0 + 1) * 16 + q * 4) = d1;
    }

    // ---- h_final (fp32) ----
    #pragma unroll
    for (int m = 0; m < 2; ++m) {
        #pragma unroll
        for (int r = 0; r < 4; ++r) {
            out[(size_t)MROWS * VOCAB + (size_t)brow * HIDDEN
                + (mt0 + m) * 16 + q * 4 + r] = hv[m][r];
        }
    }
}

extern "C" void kernel_launch(void* const* d_in, const int* in_sizes, int n_in,
                              void* d_out, int out_size, void* d_ws, size_t ws_size,
                              hipStream_t stream) {
    const int*   x      = (const int*)  d_in[0];
    const float* h0     = (const float*)d_in[1];
    const float* emb    = (const float*)d_in[2];
    const float* W_cell = (const float*)d_in[3];
    const float* b_cell = (const float*)d_in[4];
    const float* W_dec  = (const float*)d_in[5];
    const float* b_dec  = (const float*)d_in[6];
    float* out = (float*)d_out;

    float* Pe = (float*)d_ws;   // 48 KB

    pe_precompute<<<(VOCAB * HIDDEN + 127) / 128, 128, 0, stream>>>(emb, W_cell, b_cell, Pe);
    rnn_fused<<<BATCH / 16, 256, 0, stream>>>(x, h0, W_cell, W_dec, b_dec, Pe, out);
}

// Round 4
// 1737.139 us; speedup vs baseline: 1.1952x; 1.1152x over previous
//
#include <hip/hip_runtime.h>
#include <hip/hip_bf16.h>

#define VOCAB  96
#define EMBED  32
#define HIDDEN 128
#define BATCH  512
#define TLEN   2048
#define KW     (EMBED + HIDDEN)   // 160
#define MROWS  (BATCH * TLEN)     // 1,048,576

typedef __attribute__((ext_vector_type(8))) short short8;    // 8 x bf16 bits
typedef __attribute__((ext_vector_type(4))) float float4v;

static __device__ __forceinline__ unsigned short f2bf_bits(float f) {
    __hip_bfloat16 b = __float2bfloat16(f);
    return *(unsigned short*)&b;
}

// ---------------------------------------------------------------------------
// Kernel A: Pe[v][i] = b_cell[i] + sum_k emb[v,k] * We[i,k]   (96 x 128, fp32)
// ---------------------------------------------------------------------------
__global__ void pe_precompute(const float* __restrict__ emb,
                              const float* __restrict__ W_cell,
                              const float* __restrict__ b_cell,
                              float* __restrict__ Pe) {
    const int tid = blockIdx.x * blockDim.x + threadIdx.x;
    if (tid >= VOCAB * HIDDEN) return;
    const int v = tid >> 7;
    const int i = tid & (HIDDEN - 1);
    float acc = b_cell[i];
    const float* e = emb + v * EMBED;
    const float* w = W_cell + i * KW;
    #pragma unroll
    for (int k = 0; k < EMBED; ++k) acc = fmaf(e[k], w[k], acc);
    Pe[tid] = acc;
}

// ---------------------------------------------------------------------------
// Fused recurrence + decode. One block = 16 batch rows, 8 waves (512 thr,
// 2 waves/SIMD so MFMA/trans/LDS stalls of one wave hide under the other).
// Wave w: rec m-tile w (h rows w*16..w*16+15); waves 0..5 also dec v-tile w.
// MFMA operand-swapped: A = weights (m = hidden/vocab), B = h (n = batch16).
//   A-frag: A[m=lane&15][k=quad*8+j]   B-frag: B[k=quad*8+j][n=lane&15]
//   D:      D[m=quad*4+r][n=lane&15]
// h carried as exact hi+lo bf16 split. Pe[tok] (fp32, incl bias) is the MFMA
// C-init, read from GLOBAL (L2-resident) one step ahead -> no LDS conflicts.
// Tokens read from global 2 steps ahead. LDS = 16 KB h-exchange only;
// b128 reads are phase-linear (conflict-free), b64 writes <=2-way (free).
// Single s_barrier per step; no vmcnt drain in the loop.
// ---------------------------------------------------------------------------
__global__ __launch_bounds__(512, 2)
void rnn_fused(const int* __restrict__ x,
               const float* __restrict__ h0,
               const float* __restrict__ W_cell,
               const float* __restrict__ W_dec,
               const float* __restrict__ b_dec,
               const float* __restrict__ Pe,
               float* __restrict__ out) {
    __shared__ __align__(16) unsigned short hb_hi[2][16][16][8];  // 8 KB
    __shared__ __align__(16) unsigned short hb_lo[2][16][16][8];  // 8 KB

    const int tid  = threadIdx.x;
    const int w    = tid >> 6;                  // wave id = rec m-tile
    const int lane = tid & 63;
    const int l16  = lane & 15;
    const int q    = lane >> 4;
    const bool has_dec = (w < 6);               // dec v-tile = w
    const int rowbase = blockIdx.x * 16;
    const int brow = rowbase + l16;             // this lane's batch row (n-col)

    // ---- A-fragments (bf16, registers for the whole kernel) ----
    short8 Wh[4];
    {
        const float* rp = W_cell + (size_t)(w * 16 + l16) * KW + EMBED + q * 8;
        #pragma unroll
        for (int kt = 0; kt < 4; ++kt) {
            const float4 f0 = *(const float4*)(rp + kt * 32);
            const float4 f1 = *(const float4*)(rp + kt * 32 + 4);
            short8 s;
            s[0]=(short)f2bf_bits(f0.x); s[1]=(short)f2bf_bits(f0.y);
            s[2]=(short)f2bf_bits(f0.z); s[3]=(short)f2bf_bits(f0.w);
            s[4]=(short)f2bf_bits(f1.x); s[5]=(short)f2bf_bits(f1.y);
            s[6]=(short)f2bf_bits(f1.z); s[7]=(short)f2bf_bits(f1.w);
            Wh[kt] = s;
        }
    }
    short8 Wd[4];
    float4 bdec = {0.f, 0.f, 0.f, 0.f};
    if (has_dec) {
        const float* rp = W_dec + (size_t)(w * 16 + l16) * HIDDEN + q * 8;
        #pragma unroll
        for (int kt = 0; kt < 4; ++kt) {
            const float4 f0 = *(const float4*)(rp + kt * 32);
            const float4 f1 = *(const float4*)(rp + kt * 32 + 4);
            short8 s;
            s[0]=(short)f2bf_bits(f0.x); s[1]=(short)f2bf_bits(f0.y);
            s[2]=(short)f2bf_bits(f0.z); s[3]=(short)f2bf_bits(f0.w);
            s[4]=(short)f2bf_bits(f1.x); s[5]=(short)f2bf_bits(f1.y);
            s[6]=(short)f2bf_bits(f1.z); s[7]=(short)f2bf_bits(f1.w);
            Wd[kt] = s;
        }
        bdec = *(const float4*)(b_dec + w * 16 + q * 4);
    }

    // ---- initial B-frags from h0 (fp32 -> exact hi+lo split) ----
    short8 Bhi[4], Blo[4];
    #pragma unroll
    for (int kt = 0; kt < 4; ++kt) {
        const float* hp = h0 + (size_t)brow * HIDDEN + kt * 32 + q * 8;
        const float4 f0 = *(const float4*)hp;
        const float4 f1 = *(const float4*)(hp + 4);
        const float hv8[8] = {f0.x, f0.y, f0.z, f0.w, f1.x, f1.y, f1.z, f1.w};
        short8 hi, lo;
        #pragma unroll
        for (int j = 0; j < 8; ++j) {
            const unsigned hb = __float_as_uint(hv8[j]) & 0xffff0000u;
            hi[j] = (short)(hb >> 16);
            lo[j] = (short)f2bf_bits(hv8[j] - __uint_as_float(hb));
        }
        Bhi[kt] = hi; Blo[kt] = lo;
    }

    // ---- token + Pe pipeline (global, L2-resident; prefetched ahead) ----
    const int* xrow = x + (size_t)brow * TLEN;
    int tokC = xrow[0];
    int tokN = xrow[1];
    float4 pc = *(const float4*)(Pe + (size_t)tokC * HIDDEN + w * 16 + q * 4);

    float hv[4];                    // fp32 h of this wave's m-tile (h_final)

    for (int t = 0; t < TLEN; ++t) {
        // --- prefetch Pe for step t+1, token for step t+2 (global, hidden)
        const float4 pn = *(const float4*)(Pe + (size_t)tokN * HIDDEN + w * 16 + q * 4);
        const int t2 = (t + 2 < TLEN) ? t + 2 : TLEN - 1;
        const int tokN2 = xrow[t2];

        // --- recurrence: ah = Pe[tok] + Wh·h_hi ; al = Wh·h_lo (2 chains)
        float4v ah = {pc.x, pc.y, pc.z, pc.w};
        float4v al = {0.f, 0.f, 0.f, 0.f};
        #pragma unroll
        for (int kt = 0; kt < 4; ++kt) {
            ah = __builtin_amdgcn_mfma_f32_16x16x32_bf16(Wh[kt], Bhi[kt], ah, 0, 0, 0);
            al = __builtin_amdgcn_mfma_f32_16x16x32_bf16(Wh[kt], Blo[kt], al, 0, 0, 0);
        }

        // --- decode (independent; hides under tanh/split VALU)
        float4v dh = {bdec.x, bdec.y, bdec.z, bdec.w};
        float4v dl = {0.f, 0.f, 0.f, 0.f};
        if (has_dec) {
            #pragma unroll
            for (int kt = 0; kt < 4; ++kt) {
                dh = __builtin_amdgcn_mfma_f32_16x16x32_bf16(Wd[kt], Bhi[kt], dh, 0, 0, 0);
                dl = __builtin_amdgcn_mfma_f32_16x16x32_bf16(Wd[kt], Blo[kt], dl, 0, 0, 0);
            }
        }

        // --- tanh on this wave's 4 rec outputs
        #pragma unroll
        for (int r = 0; r < 4; ++r) {
            const float s = ah[r] + al[r];
            const float e = __expf(2.f * s);
            hv[r] = 1.f - __fdividef(2.f, e + 1.f);
        }

        // --- exact hi/lo split, pack, write h_{t+1} (conflict-free layout)
        const int pnb = (t & 1) ^ 1;
        {
            const unsigned b0 = __float_as_uint(hv[0]) & 0xffff0000u;
            const unsigned b1 = __float_as_uint(hv[1]) & 0xffff0000u;
            const unsigned b2 = __float_as_uint(hv[2]) & 0xffff0000u;
            const unsigned b3 = __float_as_uint(hv[3]) & 0xffff0000u;
            const float l0 = hv[0] - __uint_as_float(b0);
            const float l1 = hv[1] - __uint_as_float(b1);
            const float l2 = hv[2] - __uint_as_float(b2);
            const float l3 = hv[3] - __uint_as_float(b3);
            uint2 hw, lw;
            hw.x = (b0 >> 16) | b1;
            hw.y = (b2 >> 16) | b3;
            lw.x = (unsigned)f2bf_bits(l0) | ((unsigned)f2bf_bits(l1) << 16);
            lw.y = (unsigned)f2bf_bits(l2) | ((unsigned)f2bf_bits(l3) << 16);
            // k0 = w*16 + q*4  ->  [k0>>3][n][k0&7]
            const int kq = w * 2 + (q >> 1);
            const int j0 = (q & 1) * 4;
            *(uint2*)&hb_hi[pnb][kq][l16][j0] = hw;
            *(uint2*)&hb_lo[pnb][kq][l16][j0] = lw;
        }

        // --- fire-and-forget decode store (never drained in-loop)
        if (has_dec && t) {
            float4v d;
            d[0] = dh[0] + dl[0]; d[1] = dh[1] + dl[1];
            d[2] = dh[2] + dl[2]; d[3] = dh[3] + dl[3];
            float* op = out + ((size_t)brow * TLEN + (t - 1)) * VOCAB;
            *(float4v*)(op + w * 16 + q * 4) = d;
        }

        // LDS writes visible, barrier — WITHOUT vmcnt(0) store drain
        asm volatile("s_waitcnt lgkmcnt(0)" ::: "memory");
        __builtin_amdgcn_s_barrier();
        asm volatile("" ::: "memory");
        __builtin_amdgcn_sched_barrier(0);

        // --- next-step B-frags: phase-linear addresses (conflict-free)
        #pragma unroll
        for (int kt = 0; kt < 4; ++kt) {
            Bhi[kt] = *(const short8*)&hb_hi[pnb][kt * 4 + q][l16][0];
            Blo[kt] = *(const short8*)&hb_lo[pnb][kt * 4 + q][l16][0];
        }
        pc = pn;
        tokC = tokN; tokN = tokN2;
    }

    // ---- epilogue: decode out_{TLEN-1} from h_TLEN ----
    if (has_dec) {
        float4v dh = {bdec.x, bdec.y, bdec.z, bdec.w};
        float4v dl = {0.f, 0.f, 0.f, 0.f};
        #pragma unroll
        for (int kt = 0; kt < 4; ++kt) {
            dh = __builtin_amdgcn_mfma_f32_16x16x32_bf16(Wd[kt], Bhi[kt], dh, 0, 0, 0);
            dl = __builtin_amdgcn_mfma_f32_16x16x32_bf16(Wd[kt], Blo[kt], dl, 0, 0, 0);
        }
        float4v d;
        d[0] = dh[0] + dl[0]; d[1] = dh[1] + dl[1];
        d[2] = dh[2] + dl[2]; d[3] = dh[3] + dl[3];
        float* op = out + ((size_t)brow * TLEN + (TLEN - 1)) * VOCAB;
        *(float4v*)(op + w * 16 + q * 4) = d;
    }

    // ---- h_final (fp32): lane holds h[w*16 + q*4 + r], contiguous float4
    *(float4*)(out + (size_t)MROWS * VOCAB + (size_t)brow * HIDDEN
               + w * 16 + q * 4) = *(const float4*)hv;
}

extern "C" void kernel_launch(void* const* d_in, const int* in_sizes, int n_in,
                              void* d_out, int out_size, void* d_ws, size_t ws_size,
                              hipStream_t stream) {
    const int*   x      = (const int*)  d_in[0];
    const float* h0     = (const float*)d_in[1];
    const float* emb    = (const float*)d_in[2];
    const float* W_cell = (const float*)d_in[3];
    const float* b_cell = (const float*)d_in[4];
    const float* W_dec  = (const float*)d_in[5];
    const float* b_dec  = (const float*)d_in[6];
    float* out = (float*)d_out;

    float* Pe = (float*)d_ws;   // 48 KB (L2-resident operand in the hot loop)

    pe_precompute<<<(VOCAB * HIDDEN + 127) / 128, 128, 0, stream>>>(emb, W_cell, b_cell, Pe);
    rnn_fused<<<BATCH / 16, 512, 0, stream>>>(x, h0, W_cell, W_dec, b_dec, Pe, out);
}